// Round 6
// baseline (27.371 us; speedup 1.0000x reference)
//
#include <hip/hip_runtime.h>

// LJ pairwise energy matrix, N x N fp32 output.
// reference: disp[i,j] = q[j] - q[i], min-image, mask = (j>i) & (r2 < CUT^2),
// energy = 4*eps*((s/r)^12 - (s/r)^6) where mask else 0.
//
// Write-bound: 151 MB output at ~6.8 TB/s achievable write BW => ~22.3 us floor.
// - 4 rows per thread as TWO packed f32x2 row-pairs: clang lowers f32x2
//   fadd/fmul/fma/min to VOP3P v_pk_* (2 FP32/instr) on gfx950
// - per-wave (256-col) zero-skip of the lower triangle (~48% of matrix is
//   pure zero-store, runs at fill speed)
// - min-image via d = min(|dx|, 66-|dx|); differs from the rint() path only
//   near |dx|=33 >> cutoff -> masked, safe
// - v_rcp_f32 instead of full-precision divide (~1ulp; ~3e-2 relative
//   threshold headroom)

#define NATOMS 6144

typedef float f32x4 __attribute__((ext_vector_type(4)));
typedef float f32x2 __attribute__((ext_vector_type(2)));

__global__ __launch_bounds__(256) void lj_pair_energy(
    const float* __restrict__ q, float* __restrict__ out) {
    constexpr float CELL = 66.0f;
    constexpr float SIGMA2 = 3.405f * 3.405f;
    constexpr float EPS4 = 4.0f * 0.0103f;
    constexpr float CUT2 = 9.0f * 9.0f;

    const int i0 = blockIdx.y * 4;                        // rows i0..i0+3
    const int t  = blockIdx.x * blockDim.x + threadIdx.x; // col group (4 cols)
    const int j0 = t * 4;

    f32x4* const dst0 =
        reinterpret_cast<f32x4*>(out) + (size_t)i0 * (NATOMS / 4) + t;
    f32x4* const dst1 = dst0 + (NATOMS / 4);
    f32x4* const dst2 = dst1 + (NATOMS / 4);
    f32x4* const dst3 = dst2 + (NATOMS / 4);

    // Wave-uniform: last column covered by this wave's 64 lanes (256 cols).
    const int waveLastJ =
        (((int)(threadIdx.x & ~63u) + (int)blockIdx.x * 256) + 64) * 4 - 1;

    // All j in the wave span <= i0 <= i1..i3  =>  all four rows fully masked.
    if (i0 >= waveLastJ) {
        const f32x4 z = {0.f, 0.f, 0.f, 0.f};
        __builtin_nontemporal_store(z, dst0);
        __builtin_nontemporal_store(z, dst1);
        __builtin_nontemporal_store(z, dst2);
        __builtin_nontemporal_store(z, dst3);
        return;
    }

    // Row coords, packed as (row0,row1) and (row2,row3).
    const f32x2 qxA = {q[(i0 + 0) * 3 + 0], q[(i0 + 1) * 3 + 0]};
    const f32x2 qyA = {q[(i0 + 0) * 3 + 1], q[(i0 + 1) * 3 + 1]};
    const f32x2 qzA = {q[(i0 + 0) * 3 + 2], q[(i0 + 1) * 3 + 2]};
    const f32x2 qxB = {q[(i0 + 2) * 3 + 0], q[(i0 + 3) * 3 + 0]};
    const f32x2 qyB = {q[(i0 + 2) * 3 + 1], q[(i0 + 3) * 3 + 1]};
    const f32x2 qzB = {q[(i0 + 2) * 3 + 2], q[(i0 + 3) * 3 + 2]};

    // 4 consecutive atoms j0..j0+3: 12 contiguous floats = 3 float4 loads,
    // shared by all four rows.
    const f32x4* qv = reinterpret_cast<const f32x4*>(q + (size_t)j0 * 3);
    const f32x4 a = qv[0];
    const f32x4 b = qv[1];
    const f32x4 c = qv[2];

    const float xs[4] = {a.x, a.w, b.z, c.y};
    const float ys[4] = {a.y, b.x, b.w, c.z};
    const float zs[4] = {a.z, b.y, c.x, c.w};

    const f32x2 cell2 = {CELL, CELL};

    f32x4 e0, e1, e2, e3;
#pragma unroll
    for (int k = 0; k < 4; ++k) {
        const int j = j0 + k;
        const f32x2 jx = {xs[k], xs[k]};
        const f32x2 jy = {ys[k], ys[k]};
        const f32x2 jz = {zs[k], zs[k]};

        // pair A: rows i0, i0+1
        const f32x2 axA = __builtin_elementwise_abs(jx - qxA);
        const f32x2 ayA = __builtin_elementwise_abs(jy - qyA);
        const f32x2 azA = __builtin_elementwise_abs(jz - qzA);
        const f32x2 dxA = __builtin_elementwise_min(axA, cell2 - axA);
        const f32x2 dyA = __builtin_elementwise_min(ayA, cell2 - ayA);
        const f32x2 dzA = __builtin_elementwise_min(azA, cell2 - azA);
        const f32x2 r2A = __builtin_elementwise_fma(
            dxA, dxA, __builtin_elementwise_fma(dyA, dyA, dzA * dzA));

        // pair B: rows i0+2, i0+3
        const f32x2 axB = __builtin_elementwise_abs(jx - qxB);
        const f32x2 ayB = __builtin_elementwise_abs(jy - qyB);
        const f32x2 azB = __builtin_elementwise_abs(jz - qzB);
        const f32x2 dxB = __builtin_elementwise_min(axB, cell2 - axB);
        const f32x2 dyB = __builtin_elementwise_min(ayB, cell2 - ayB);
        const f32x2 dzB = __builtin_elementwise_min(azB, cell2 - azB);
        const f32x2 r2B = __builtin_elementwise_fma(
            dxB, dxB, __builtin_elementwise_fma(dyB, dyB, dzB * dzB));

        // reciprocal: scalar v_rcp_f32 per element (no packed transcendental)
        const f32x2 sr2A = {SIGMA2 * __builtin_amdgcn_rcpf(r2A.x),
                            SIGMA2 * __builtin_amdgcn_rcpf(r2A.y)};
        const f32x2 sr2B = {SIGMA2 * __builtin_amdgcn_rcpf(r2B.x),
                            SIGMA2 * __builtin_amdgcn_rcpf(r2B.y)};

        const f32x2 sr6A = sr2A * sr2A * sr2A;
        const f32x2 sr6B = sr2B * sr2B * sr2B;
        const f32x2 enA =
            __builtin_elementwise_fma(sr6A, sr6A, -sr6A) * EPS4;
        const f32x2 enB =
            __builtin_elementwise_fma(sr6B, sr6B, -sr6B) * EPS4;

        e0[k] = ((j > i0 + 0) && (r2A.x < CUT2)) ? enA.x : 0.0f;
        e1[k] = ((j > i0 + 1) && (r2A.y < CUT2)) ? enA.y : 0.0f;
        e2[k] = ((j > i0 + 2) && (r2B.x < CUT2)) ? enB.x : 0.0f;
        e3[k] = ((j > i0 + 3) && (r2B.y < CUT2)) ? enB.y : 0.0f;
    }

    __builtin_nontemporal_store(e0, dst0);
    __builtin_nontemporal_store(e1, dst1);
    __builtin_nontemporal_store(e2, dst2);
    __builtin_nontemporal_store(e3, dst3);
}

extern "C" void kernel_launch(void* const* d_in, const int* in_sizes, int n_in,
                              void* d_out, int out_size, void* d_ws, size_t ws_size,
                              hipStream_t stream) {
    const float* q = (const float*)d_in[0];
    float* out = (float*)d_out;

    dim3 block(256, 1, 1);
    dim3 grid(NATOMS / (4 * 256), NATOMS / 4, 1); // (6, 1536)
    lj_pair_energy<<<grid, block, 0, stream>>>(q, out);
}

// Round 7
// 26.172 us; speedup vs baseline: 1.0458x; 1.0458x over previous
//
#include <hip/hip_runtime.h>

// LJ pairwise energy matrix, N x N fp32 output.
// reference: disp[i,j] = q[j] - q[i], min-image, mask = (j>i) & (r2 < CUT^2),
// energy = 4*eps*((s/r)^12 - (s/r)^6) where mask else 0.
//
// Write-bound: 151 MB output at ~6.7 TB/s achievable write BW => ~22.3 us floor.
// Fill-kernel-style streaming: 1024 blocks (4/CU), each owns 6 consecutive
// full rows = 144 KB contiguous output; loops 6 col-steps x 6 rows.
// - j-atom coords loaded once per col-step, reused across 6 rows
// - per-(wave,row) zero-skip of the lower triangle (wave-uniform branch)
// - min-image via d = min(|dx|, 66-|dx|); differs from the rint() path only
//   near |dx|=33 >> cutoff -> masked, safe
// - v_rcp_f32 instead of divide (~1ulp; ~3e-2 relative threshold headroom)

#define NATOMS 6144
#define NF4 (NATOMS / 4)       // 1536 float4 per row
#define ROWS_PER_BLOCK 6
#define COL_STEPS 6            // 256 threads * 4 cols * 6 = 6144 cols

typedef float f32x4 __attribute__((ext_vector_type(4)));

__global__ __launch_bounds__(256) void lj_pair_energy(
    const float* __restrict__ q, float* __restrict__ out) {
    constexpr float CELL = 66.0f;
    constexpr float SIGMA2 = 3.405f * 3.405f;
    constexpr float EPS4 = 4.0f * 0.0103f;
    constexpr float CUT2 = 9.0f * 9.0f;

    const int r0 = blockIdx.x * ROWS_PER_BLOCK;
    const int t  = threadIdx.x;
    // wave-uniform base lane group (SGPR) for the skip test
    const int w64 = __builtin_amdgcn_readfirstlane(t & ~63);

    f32x4* const out4 = reinterpret_cast<f32x4*>(out);

#pragma unroll 1
    for (int s = 0; s < COL_STEPS; ++s) {
        const int tj = t + 256 * s;   // float4 index within the row
        const int j0 = tj * 4;
        // last column j covered by this wave at this col-step
        const int lastJ = (w64 + 63 + 256 * s) * 4 + 3;

        // 4 consecutive atoms: 12 contiguous floats = 3 float4 loads,
        // shared across the 6 rows below.
        const f32x4* qv = reinterpret_cast<const f32x4*>(q + (size_t)j0 * 3);
        const f32x4 a = qv[0];
        const f32x4 b = qv[1];
        const f32x4 c = qv[2];
        const float xs[4] = {a.x, a.w, b.z, c.y};
        const float ys[4] = {a.y, b.x, b.w, c.z};
        const float zs[4] = {a.z, b.y, c.x, c.w};

#pragma unroll
        for (int r = 0; r < ROWS_PER_BLOCK; ++r) {
            const int i = r0 + r;
            f32x4* const dst = out4 + (size_t)i * NF4 + tj;

            if (i >= lastJ) {  // whole wave span masked: pure zero store
                __builtin_nontemporal_store((f32x4){0.f, 0.f, 0.f, 0.f}, dst);
                continue;
            }

            // q[i] — block-uniform scalar loads (cache-resident)
            const float qix = q[i * 3 + 0];
            const float qiy = q[i * 3 + 1];
            const float qiz = q[i * 3 + 2];

            f32x4 e;
#pragma unroll
            for (int k = 0; k < 4; ++k) {
                const float ax = xs[k] - qix;
                const float ay = ys[k] - qiy;
                const float az = zs[k] - qiz;
                const float dx = fminf(fabsf(ax), CELL - fabsf(ax));
                const float dy = fminf(fabsf(ay), CELL - fabsf(ay));
                const float dz = fminf(fabsf(az), CELL - fabsf(az));
                const float r2 = fmaf(dx, dx, fmaf(dy, dy, dz * dz));
                const bool m = ((j0 + k) > i) && (r2 < CUT2);
                const float sr2 = SIGMA2 * __builtin_amdgcn_rcpf(r2);
                const float sr6 = sr2 * sr2 * sr2;
                e[k] = m ? EPS4 * fmaf(sr6, sr6, -sr6) : 0.0f;
            }
            __builtin_nontemporal_store(e, dst);
        }
    }
}

extern "C" void kernel_launch(void* const* d_in, const int* in_sizes, int n_in,
                              void* d_out, int out_size, void* d_ws, size_t ws_size,
                              hipStream_t stream) {
    const float* q = (const float*)d_in[0];
    float* out = (float*)d_out;

    dim3 block(256, 1, 1);
    dim3 grid(NATOMS / ROWS_PER_BLOCK, 1, 1); // 1024 blocks, 4/CU
    lj_pair_energy<<<grid, block, 0, stream>>>(q, out);
}